// Round 1
// baseline (427.974 us; speedup 1.0000x reference)
//
#include <hip/hip_runtime.h>

#define N_NODES 50000
#define N_EDGES 500000
#define D_NODE 64
#define D_EDGE 32
#define MSG_DIM 160
#define HID_DIM 224
#define ALPHA 0.01f

#define EPB 64          // edges per block (edge kernel)
#define NPB 64          // nodes per block (update kernel)
#define A_STRIDE 168    // 160 + 8 pad (shorts) -> 336B rows, conflict-free b128 frags
#define W_STRIDE 168
#define AH_STRIDE 232   // 224 + 8 pad

typedef unsigned short u16;
typedef short short8 __attribute__((ext_vector_type(8)));
typedef float float4v __attribute__((ext_vector_type(4)));

static __device__ __forceinline__ u16 f2bf(float f) {
    unsigned int u = __float_as_uint(f);
    u += 0x7fffu + ((u >> 16) & 1u);   // round-to-nearest-even
    return (u16)(u >> 16);
}

// generic f32 -> bf16 converter, 4 elems/thread
__global__ __launch_bounds__(256) void cvt_bf16(const float* __restrict__ in,
                                                u16* __restrict__ out, int n4) {
    int i = blockIdx.x * 256 + threadIdx.x;
    if (i < n4) {
        float4 v = reinterpret_cast<const float4*>(in)[i];
        ushort4 o;
        o.x = f2bf(v.x); o.y = f2bf(v.y); o.z = f2bf(v.z); o.w = f2bf(v.w);
        reinterpret_cast<ushort4*>(out)[i] = o;
    }
}

// ---------------- edge message kernel ----------------
// C[e][i] = leaky( sum_k [h_src|h_dst|h_e][e][k] * W_msg[i][k] + b_msg[i] )
// atomicAdd into m_sum[dst[e]][i]
__global__ __launch_bounds__(256) void edge_msg_kernel(
    const u16* __restrict__ hn_bf, const float* __restrict__ h_e,
    const int* __restrict__ src, const int* __restrict__ dst,
    const u16* __restrict__ Wm_bf, const float* __restrict__ b_msg,
    float* __restrict__ m_sum)
{
    __shared__ alignas(16) u16 A_lds[EPB * A_STRIDE];
    __shared__ alignas(16) u16 Wc[32 * W_STRIDE];

    const int tid = threadIdx.x;
    const int e0 = blockIdx.x * EPB;

    // ---- stage A tile: 64 edges x 160 bf16 (4 threads per edge) ----
    {
        const int e_loc = tid >> 2, j = tid & 3;
        int e = e0 + e_loc; if (e > N_EDGES - 1) e = N_EDGES - 1;
        const int s = src[e], d = dst[e];
        const uint4* srow = reinterpret_cast<const uint4*>(hn_bf + (size_t)s * D_NODE);
        const uint4* drow = reinterpret_cast<const uint4*>(hn_bf + (size_t)d * D_NODE);
        uint4* Arow = reinterpret_cast<uint4*>(&A_lds[e_loc * A_STRIDE]);
        Arow[j * 2]     = srow[j * 2];        // bf16 [0,64): h_n[src]
        Arow[j * 2 + 1] = srow[j * 2 + 1];
        Arow[8 + j * 2]     = drow[j * 2];    // bf16 [64,128): h_n[dst]
        Arow[8 + j * 2 + 1] = drow[j * 2 + 1];
        const float4* he = reinterpret_cast<const float4*>(h_e + (size_t)e * D_EDGE);
        float4 p = he[j * 2], q = he[j * 2 + 1];
        ushort4 lo, hi;
        lo.x = f2bf(p.x); lo.y = f2bf(p.y); lo.z = f2bf(p.z); lo.w = f2bf(p.w);
        hi.x = f2bf(q.x); hi.y = f2bf(q.y); hi.z = f2bf(q.z); hi.w = f2bf(q.w);
        ushort4* Aus = reinterpret_cast<ushort4*>(Arow);
        Aus[32 + j * 2]     = lo;             // bf16 [128,160): h_e
        Aus[32 + j * 2 + 1] = hi;
    }
    __syncthreads();

    const int wave = tid >> 6, lane = tid & 63;
    const int qd = lane >> 4, l15 = lane & 15;

    // A fragments for this wave's 16 edges, all 5 K-steps (kept in regs)
    short8 a_frag[5];
#pragma unroll
    for (int ks = 0; ks < 5; ++ks)
        a_frag[ks] = *reinterpret_cast<const short8*>(
            &A_lds[(wave * 16 + l15) * A_STRIDE + ks * 32 + qd * 8]);

    int dstv[4]; bool okr[4];
#pragma unroll
    for (int r = 0; r < 4; ++r) {
        int e = e0 + wave * 16 + qd * 4 + r;
        okr[r] = (e < N_EDGES);
        if (e > N_EDGES - 1) e = N_EDGES - 1;
        dstv[r] = dst[e];
    }

    for (int c = 0; c < 5; ++c) {            // 5 chunks of 32 output features
        if (c) __syncthreads();
        for (int f = tid; f < 32 * 20; f += 256) {   // stage W rows [c*32, c*32+32)
            int row = f / 20, col = f % 20;
            reinterpret_cast<uint4*>(&Wc[row * W_STRIDE])[col] =
                reinterpret_cast<const uint4*>(Wm_bf)[(c * 32 + row) * 20 + col];
        }
        __syncthreads();

#pragma unroll
        for (int it2 = 0; it2 < 2; ++it2) {
            const int i = c * 32 + it2 * 16 + l15;
            float4v acc = {0.f, 0.f, 0.f, 0.f};
#pragma unroll
            for (int ks = 0; ks < 5; ++ks) {
                short8 b = *reinterpret_cast<const short8*>(
                    &Wc[(it2 * 16 + l15) * W_STRIDE + ks * 32 + qd * 8]);
                acc = __builtin_amdgcn_mfma_f32_16x16x32_bf16(a_frag[ks], b, acc, 0, 0, 0);
            }
            const float bias = b_msg[i];
#pragma unroll
            for (int r = 0; r < 4; ++r) {
                if (okr[r]) {
                    float v = acc[r] + bias;
                    v = v > 0.f ? v : ALPHA * v;
                    atomicAdd(&m_sum[(size_t)dstv[r] * MSG_DIM + i], v);
                }
            }
        }
    }
}

// ---------------- node update kernel ----------------
// out[n][i] = leaky( sum_k [m_sum|h_n][n][k] * W_hid[i][k] + b_hid[i] )
__global__ __launch_bounds__(256) void update_kernel(
    const float* __restrict__ m_sum, const u16* __restrict__ hn_bf,
    const u16* __restrict__ Wh_bf, const float* __restrict__ b_hid,
    float* __restrict__ out)
{
    __shared__ alignas(16) u16 A_lds[NPB * AH_STRIDE];
    const int tid = threadIdx.x;
    const int n0 = blockIdx.x * NPB;

    {   // stage 64 nodes x 224 bf16 (4 threads per node)
        const int n_loc = tid >> 2, j = tid & 3;
        int n = n0 + n_loc; if (n > N_NODES - 1) n = N_NODES - 1;
        const float4* mrow = reinterpret_cast<const float4*>(m_sum + (size_t)n * MSG_DIM);
        uint4* Au = reinterpret_cast<uint4*>(&A_lds[n_loc * AH_STRIDE]);
        ushort4* Aus = reinterpret_cast<ushort4*>(Au);
#pragma unroll
        for (int p = 0; p < 5; ++p) {        // bf16 [0,160): m_sum (fp32->bf16)
            float4 x = mrow[j * 10 + p * 2], y = mrow[j * 10 + p * 2 + 1];
            ushort4 lo, hi;
            lo.x = f2bf(x.x); lo.y = f2bf(x.y); lo.z = f2bf(x.z); lo.w = f2bf(x.w);
            hi.x = f2bf(y.x); hi.y = f2bf(y.y); hi.z = f2bf(y.z); hi.w = f2bf(y.w);
            Aus[(j * 5 + p) * 2]     = lo;
            Aus[(j * 5 + p) * 2 + 1] = hi;
        }
        const uint4* hrow = reinterpret_cast<const uint4*>(hn_bf + (size_t)n * D_NODE);
        Au[20 + j * 2]     = hrow[j * 2];    // bf16 [160,224): h_n
        Au[20 + j * 2 + 1] = hrow[j * 2 + 1];
    }
    __syncthreads();

    const int wave = tid >> 6, lane = tid & 63;
    const int qd = lane >> 4, l15 = lane & 15;

    short8 a_frag[7];
#pragma unroll
    for (int ks = 0; ks < 7; ++ks)
        a_frag[ks] = *reinterpret_cast<const short8*>(
            &A_lds[(wave * 16 + l15) * AH_STRIDE + ks * 32 + qd * 8]);

    for (int it = 0; it < 14; ++it) {
        const int i = it * 16 + l15;
        float4v acc = {0.f, 0.f, 0.f, 0.f};
#pragma unroll
        for (int ks = 0; ks < 7; ++ks) {
            short8 b = *reinterpret_cast<const short8*>(
                Wh_bf + (size_t)i * HID_DIM + ks * 32 + qd * 8);
            acc = __builtin_amdgcn_mfma_f32_16x16x32_bf16(a_frag[ks], b, acc, 0, 0, 0);
        }
        const float bias = b_hid[i];
#pragma unroll
        for (int r = 0; r < 4; ++r) {
            const int n = n0 + wave * 16 + qd * 4 + r;
            if (n < N_NODES) {
                float v = acc[r] + bias;
                v = v > 0.f ? v : ALPHA * v;
                out[(size_t)n * HID_DIM + i] = v;
            }
        }
    }
}

extern "C" void kernel_launch(void* const* d_in, const int* in_sizes, int n_in,
                              void* d_out, int out_size, void* d_ws, size_t ws_size,
                              hipStream_t stream)
{
    const float* h_n   = (const float*)d_in[0];
    const float* h_e   = (const float*)d_in[1];
    const int*   src   = (const int*)d_in[2];
    const int*   dst   = (const int*)d_in[3];
    const float* W_msg = (const float*)d_in[4];
    const float* b_msg = (const float*)d_in[5];
    const float* W_hid = (const float*)d_in[6];
    const float* b_hid = (const float*)d_in[7];
    float* out = (float*)d_out;

    char* ws = (char*)d_ws;
    float* m_sum = (float*)ws;                       // 50000*160*4 = 32,000,000 B
    u16*   hn_bf = (u16*)(ws + 32000000);            // 50000*64*2  =  6,400,000 B
    u16*   Wm_bf = (u16*)(ws + 38400000);            // 160*160*2   =     51,200 B
    u16*   Wh_bf = (u16*)(ws + 38451200);            // 224*224*2   =    100,352 B

    hipMemsetAsync(m_sum, 0, (size_t)N_NODES * MSG_DIM * sizeof(float), stream);
    cvt_bf16<<<(N_NODES * D_NODE / 4 + 255) / 256, 256, 0, stream>>>(h_n, hn_bf, N_NODES * D_NODE / 4);
    cvt_bf16<<<(MSG_DIM * MSG_DIM / 4 + 255) / 256, 256, 0, stream>>>(W_msg, Wm_bf, MSG_DIM * MSG_DIM / 4);
    cvt_bf16<<<(HID_DIM * HID_DIM / 4 + 255) / 256, 256, 0, stream>>>(W_hid, Wh_bf, HID_DIM * HID_DIM / 4);

    edge_msg_kernel<<<(N_EDGES + EPB - 1) / EPB, 256, 0, stream>>>(
        hn_bf, h_e, src, dst, Wm_bf, b_msg, m_sum);
    update_kernel<<<(N_NODES + NPB - 1) / NPB, 256, 0, stream>>>(
        m_sum, hn_bf, Wh_bf, b_hid, out);
}